// Round 1
// baseline (251472.754 us; speedup 1.0000x reference)
//
#include <hip/hip_runtime.h>
#include <math.h>

// ---------------------------------------------------------------------------
// FullModelTest: 4 stacked LSTM cells (H=48,96,144,48) + 3 FF blocks,
// T=200 sequential steps, B=4096 batch. Batch rows are independent, so each
// block owns 16 rows and loops over all timesteps with state in LDS.
// Round 1: fp32 VALU, weights pre-transposed to [K][N] in workspace.
// ---------------------------------------------------------------------------

#define T_STEPS 200
#define BATCH 4096
#define M_ROWS 16   // rows per block

// workspace float offsets (weights transposed to [K][N], biases combined)
#define L1WT 0
#define L1B  18432
#define L2WT 18624
#define L2B  92352
#define L3WT 92736
#define L3B  258624
#define L4WT 259200
#define L4B  277632
#define F1W1 277824
#define F1B1 278112
#define F1W2 278160
#define F1B2 280464
#define F2W1 280512
#define F2B1 301248
#define F2W2 301392
#define F2B2 315216
#define F3W1 315312
#define F3B1 324528
#define F3W2 324624
#define F3B2 329232

__device__ __forceinline__ float sigf(float x) {
    return 1.0f / (1.0f + __expf(-x));
}

// ---------------------------------------------------------------------------
// Prep: build Wt[k][c] = [wih^T ; whh^T] (K = Din+H rows, N = 4H cols),
// bias[c] = bih[c] + bhh[c].
// ---------------------------------------------------------------------------
__global__ void prep_lstm(const float* __restrict__ wih, const float* __restrict__ whh,
                          const float* __restrict__ bih, const float* __restrict__ bhh,
                          float* __restrict__ Wt, float* __restrict__ bias,
                          int Din, int H) {
    int N = 4 * H;
    int K = Din + H;
    int total = K * N;
    for (int idx = blockIdx.x * blockDim.x + threadIdx.x; idx < total + N;
         idx += gridDim.x * blockDim.x) {
        if (idx < total) {
            int k = idx / N;
            int c = idx - k * N;
            Wt[idx] = (k < Din) ? wih[c * Din + k] : whh[c * H + (k - Din)];
        } else {
            int c = idx - total;
            bias[c] = bih[c] + bhh[c];
        }
    }
}

__global__ void prep_ff(const float* __restrict__ w, const float* __restrict__ b,
                        float* __restrict__ Wt, float* __restrict__ bias,
                        int K, int N) {
    int total = K * N;
    for (int idx = blockIdx.x * blockDim.x + threadIdx.x; idx < total + N;
         idx += gridDim.x * blockDim.x) {
        if (idx < total) {
            int k = idx / N;
            int c = idx - k * N;
            Wt[idx] = w[c * K + k];
        } else {
            int c = idx - total;
            bias[c] = b[c];
        }
    }
}

// ---------------------------------------------------------------------------
// Fused LSTM layer for 16 rows. Thread (r=tid>>4, c0=tid&15) accumulates all
// four gates for cols c0+16m in registers; input x is a virtual concat of up
// to 3 LDS segments (input / upstream h / recurrent h). Internal barrier
// between accumulate and the h/c write protects the recurrent read.
// ---------------------------------------------------------------------------
template <int H>
__device__ __forceinline__ void lstm_layer(
    const float* __restrict__ Wt, const float* __restrict__ bias,
    const float* __restrict__ xa, int stra, int Ka,
    const float* __restrict__ xb, int strb, int Kb,
    const float* __restrict__ xc, int strc, int Kc,
    float* __restrict__ h, float* __restrict__ c, int tid) {
    constexpr int N = 4 * H;
    constexpr int NC = H / 16;
    const int r = tid >> 4;
    const int c0 = tid & 15;

    float ai[NC], af[NC], ag[NC], ao[NC];
#pragma unroll
    for (int m = 0; m < NC; ++m) {
        ai[m] = bias[c0 + 16 * m];
        af[m] = bias[c0 + 16 * m + H];
        ag[m] = bias[c0 + 16 * m + 2 * H];
        ao[m] = bias[c0 + 16 * m + 3 * H];
    }

    const float* wp = Wt + c0;
    auto seg = [&](const float* xbase, int stride, int K) {
        const float* xr = xbase + r * stride;
        for (int k = 0; k < K; ++k) {
            float xv = xr[k];
#pragma unroll
            for (int m = 0; m < NC; ++m) {
                ai[m] = fmaf(xv, wp[16 * m], ai[m]);
                af[m] = fmaf(xv, wp[16 * m + H], af[m]);
                ag[m] = fmaf(xv, wp[16 * m + 2 * H], ag[m]);
                ao[m] = fmaf(xv, wp[16 * m + 3 * H], ao[m]);
            }
            wp += N;
        }
    };
    seg(xa, stra, Ka);
    seg(xb, strb, Kb);
    seg(xc, strc, Kc);

    __syncthreads();  // all reads of h (recurrent segment) done before writes

#pragma unroll
    for (int m = 0; m < NC; ++m) {
        int j = c0 + 16 * m;
        float ig = sigf(ai[m]);
        float fg = sigf(af[m]);
        float gg = tanhf(ag[m]);
        float og = sigf(ao[m]);
        float cv = fmaf(fg, c[r * H + j], ig * gg);
        c[r * H + j] = cv;
        h[r * H + j] = og * tanhf(cv);
    }
}

// FF layer: out[16][N] = relu(x[16][K] @ Wt + bias). Caller syncs afterwards.
template <int N>
__device__ __forceinline__ void ff_layer(
    const float* __restrict__ Wt, const float* __restrict__ bias,
    const float* __restrict__ x, int strx, int K,
    float* __restrict__ out, int tid) {
    constexpr int NC = N / 16;
    const int r = tid >> 4;
    const int c0 = tid & 15;
    float acc[NC];
#pragma unroll
    for (int m = 0; m < NC; ++m) acc[m] = bias[c0 + 16 * m];
    const float* wp = Wt + c0;
    const float* xr = x + r * strx;
    for (int k = 0; k < K; ++k) {
        float xv = xr[k];
#pragma unroll
        for (int m = 0; m < NC; ++m) acc[m] = fmaf(xv, wp[16 * m], acc[m]);
        wp += N;
    }
#pragma unroll
    for (int m = 0; m < NC; ++m) out[r * N + c0 + 16 * m] = fmaxf(acc[m], 0.0f);
}

// ---------------------------------------------------------------------------
// Main persistent kernel: one block = 16 batch rows, loops t = 0..199.
// Static LDS = 16128 floats = 64512 B.
// ---------------------------------------------------------------------------
__global__ __launch_bounds__(256) void model_kernel(
    const float* __restrict__ tactiles, const float* __restrict__ actions,
    const float* __restrict__ context, const float* __restrict__ ws,
    const float* __restrict__ h01, const float* __restrict__ c01,
    const float* __restrict__ h02, const float* __restrict__ c02,
    const float* __restrict__ h03, const float* __restrict__ c03,
    const float* __restrict__ h04, const float* __restrict__ c04,
    float* __restrict__ out) {
    __shared__ float h1s[16 * 48], c1s[16 * 48];
    __shared__ float h2s[16 * 96], c2s[16 * 96];
    __shared__ float h3s[16 * 144], c3s[16 * 144];
    __shared__ float h4s[16 * 48], c4s[16 * 48];
    __shared__ float buf768[16 * 48];   // x1 tile / ctx tile / out5
    __shared__ float saoutb[16 * 48];   // f1 output (needed until L3)
    __shared__ float tbuf[16 * 144];    // sa(96)+sahid / f2 hidden / f3 hidden
    __shared__ float out4b[16 * 96];    // f2 output

    const int tid = threadIdx.x;
    const int r0 = blockIdx.x * M_ROWS;

    // load initial states (layouts match: [16][H] contiguous)
    for (int i = tid; i < 768; i += 256) {
        h1s[i] = h01[(size_t)r0 * 48 + i];
        c1s[i] = c01[(size_t)r0 * 48 + i];
        h4s[i] = h04[(size_t)r0 * 48 + i];
        c4s[i] = c04[(size_t)r0 * 48 + i];
    }
    for (int i = tid; i < 1536; i += 256) {
        h2s[i] = h02[(size_t)r0 * 96 + i];
        c2s[i] = c02[(size_t)r0 * 96 + i];
    }
    for (int i = tid; i < 2304; i += 256) {
        h3s[i] = h03[(size_t)r0 * 144 + i];
        c3s[i] = c03[(size_t)r0 * 144 + i];
    }
    __syncthreads();

    const float* l1Wt = ws + L1WT;  const float* l1b = ws + L1B;
    const float* l2Wt = ws + L2WT;  const float* l2b = ws + L2B;
    const float* l3Wt = ws + L3WT;  const float* l3b = ws + L3B;
    const float* l4Wt = ws + L4WT;  const float* l4b = ws + L4B;

    for (int t = 0; t < T_STEPS; ++t) {
        // x1 tile: tactiles for t<6, else previous h4 (out6)
        if (t < 6) {
            const float* src = tactiles + (size_t)t * (BATCH * 48) + (size_t)r0 * 48;
            for (int i = tid; i < 768; i += 256) buf768[i] = src[i];
        } else {
            for (int i = tid; i < 768; i += 256) buf768[i] = h4s[i];
        }
        // sa = [state(=actions[0]) | actions[t]] into tbuf[0:96], stride 6
        if (tid < 96) {
            int r = tid / 6;
            int d = tid - r * 6;
            tbuf[tid] = (d < 3)
                ? actions[(size_t)(r0 + r) * 3 + d]
                : actions[(size_t)t * (BATCH * 3) + (size_t)(r0 + r) * 3 + (d - 3)];
        }
        __syncthreads();

        // f1: 6 -> 48 -> 48 (relu, relu)
        ff_layer<48>(ws + F1W1, ws + F1B1, tbuf, 6, 6, tbuf + 96, tid);
        __syncthreads();
        ff_layer<48>(ws + F1W2, ws + F1B2, tbuf + 96, 48, 48, saoutb, tid);
        // (saoutb consumed at L3; barriers in between cover it)

        // L1: x = [x1 | h1_old]
        lstm_layer<48>(l1Wt, l1b, buf768, 48, 48, h1s, 48, 48, h1s, 48, 0,
                       h1s, c1s, tid);
        __syncthreads();

        // ctx tile into buf768 (x1 tile dead)
        {
            const float* src = context + (size_t)t * (BATCH * 48) + (size_t)r0 * 48;
            for (int i = tid; i < 768; i += 256) buf768[i] = src[i];
        }
        __syncthreads();

        // L2: x = [ctx | h1_new | h2_old]
        lstm_layer<96>(l2Wt, l2b, buf768, 48, 48, h1s, 48, 48, h2s, 96, 96,
                       h2s, c2s, tid);
        __syncthreads();

        // L3: x = [sa_out | h2_new | h3_old]
        lstm_layer<144>(l3Wt, l3b, saoutb, 48, 48, h2s, 96, 96, h3s, 144, 144,
                        h3s, c3s, tid);
        __syncthreads();

        // f2: 144 -> 144 -> 96
        ff_layer<144>(ws + F2W1, ws + F2B1, h3s, 144, 144, tbuf, tid);
        __syncthreads();
        ff_layer<96>(ws + F2W2, ws + F2B2, tbuf, 144, 144, out4b, tid);
        __syncthreads();

        // f3: 96 -> 96 -> 48
        ff_layer<96>(ws + F3W1, ws + F3B1, out4b, 96, 96, tbuf, tid);
        __syncthreads();
        ff_layer<48>(ws + F3W2, ws + F3B2, tbuf, 96, 96, buf768, tid);  // out5
        __syncthreads();

        // L4: x = [out5 | h4_old]
        lstm_layer<48>(l4Wt, l4b, buf768, 48, 48, h4s, 48, 48, h4s, 48, 0,
                       h4s, c4s, tid);
        __syncthreads();

        // emit h4
        {
            float* dst = out + (size_t)t * (BATCH * 48) + (size_t)r0 * 48;
            for (int i = tid; i < 768; i += 256) dst[i] = h4s[i];
        }
        __syncthreads();
    }
}

// ---------------------------------------------------------------------------
extern "C" void kernel_launch(void* const* d_in, const int* in_sizes, int n_in,
                              void* d_out, int out_size, void* d_ws, size_t ws_size,
                              hipStream_t stream) {
    const float* tac = (const float*)d_in[0];
    const float* act = (const float*)d_in[1];
    const float* ctx = (const float*)d_in[2];

    const float* l1_wih = (const float*)d_in[3];
    const float* l1_whh = (const float*)d_in[4];
    const float* l1_bih = (const float*)d_in[5];
    const float* l1_bhh = (const float*)d_in[6];
    const float* l2_wih = (const float*)d_in[7];
    const float* l2_whh = (const float*)d_in[8];
    const float* l2_bih = (const float*)d_in[9];
    const float* l2_bhh = (const float*)d_in[10];
    const float* l3_wih = (const float*)d_in[11];
    const float* l3_whh = (const float*)d_in[12];
    const float* l3_bih = (const float*)d_in[13];
    const float* l3_bhh = (const float*)d_in[14];
    const float* l4_wih = (const float*)d_in[15];
    const float* l4_whh = (const float*)d_in[16];
    const float* l4_bih = (const float*)d_in[17];
    const float* l4_bhh = (const float*)d_in[18];

    const float* f1_w1 = (const float*)d_in[19];
    const float* f1_b1 = (const float*)d_in[20];
    const float* f1_w2 = (const float*)d_in[21];
    const float* f1_b2 = (const float*)d_in[22];
    const float* f2_w1 = (const float*)d_in[23];
    const float* f2_b1 = (const float*)d_in[24];
    const float* f2_w2 = (const float*)d_in[25];
    const float* f2_b2 = (const float*)d_in[26];
    const float* f3_w1 = (const float*)d_in[27];
    const float* f3_b1 = (const float*)d_in[28];
    const float* f3_w2 = (const float*)d_in[29];
    const float* f3_b2 = (const float*)d_in[30];

    const float* h01 = (const float*)d_in[31];
    const float* c01 = (const float*)d_in[32];
    const float* h02 = (const float*)d_in[33];
    const float* c02 = (const float*)d_in[34];
    const float* h03 = (const float*)d_in[35];
    const float* c03 = (const float*)d_in[36];
    const float* h04 = (const float*)d_in[37];
    const float* c04 = (const float*)d_in[38];

    float* ws = (float*)d_ws;
    float* out = (float*)d_out;

    dim3 blk(256);
    hipLaunchKernelGGL(prep_lstm, dim3(64), blk, 0, stream,
                       l1_wih, l1_whh, l1_bih, l1_bhh, ws + L1WT, ws + L1B, 48, 48);
    hipLaunchKernelGGL(prep_lstm, dim3(128), blk, 0, stream,
                       l2_wih, l2_whh, l2_bih, l2_bhh, ws + L2WT, ws + L2B, 96, 96);
    hipLaunchKernelGGL(prep_lstm, dim3(256), blk, 0, stream,
                       l3_wih, l3_whh, l3_bih, l3_bhh, ws + L3WT, ws + L3B, 144, 144);
    hipLaunchKernelGGL(prep_lstm, dim3(64), blk, 0, stream,
                       l4_wih, l4_whh, l4_bih, l4_bhh, ws + L4WT, ws + L4B, 48, 48);

    hipLaunchKernelGGL(prep_ff, dim3(4), blk, 0, stream,
                       f1_w1, f1_b1, ws + F1W1, ws + F1B1, 6, 48);
    hipLaunchKernelGGL(prep_ff, dim3(16), blk, 0, stream,
                       f1_w2, f1_b2, ws + F1W2, ws + F1B2, 48, 48);
    hipLaunchKernelGGL(prep_ff, dim3(96), blk, 0, stream,
                       f2_w1, f2_b1, ws + F2W1, ws + F2B1, 144, 144);
    hipLaunchKernelGGL(prep_ff, dim3(64), blk, 0, stream,
                       f2_w2, f2_b2, ws + F2W2, ws + F2B2, 144, 96);
    hipLaunchKernelGGL(prep_ff, dim3(48), blk, 0, stream,
                       f3_w1, f3_b1, ws + F3W1, ws + F3B1, 96, 96);
    hipLaunchKernelGGL(prep_ff, dim3(24), blk, 0, stream,
                       f3_w2, f3_b2, ws + F3W2, ws + F3B2, 96, 48);

    hipLaunchKernelGGL(model_kernel, dim3(BATCH / M_ROWS), blk, 0, stream,
                       tac, act, ctx, ws,
                       h01, c01, h02, c02, h03, c03, h04, c04, out);
}

// Round 2
// 20119.777 us; speedup vs baseline: 12.4988x; 12.4988x over previous
//
#include <hip/hip_runtime.h>
#include <math.h>

// ---------------------------------------------------------------------------
// FullModelTest: 4 stacked LSTMs (H=48,96,144,48) + 3 FF blocks, T=200, B=4096.
// Round 2: column-mapped matmuls. Thread = output column(s); weight row
// W[c][k] streamed from global as contiguous float4 (1 load / 64-192 FMAs);
// activations x^T[k][r] in LDS (stride-18 rows, bank-conflict-free), read as
// broadcast float2. c-states in registers (fixed ownership), gates combined
// via a stride-17 LDS pool. L3 computed in two 8-row passes.
// ---------------------------------------------------------------------------

#define NT 256
#define MROWS 16
#define TSTEPS 200
#define BATCH 4096
#define XS 18      // x^T row stride (floats), coprime with 32 banks, float2-aligned
#define GS 17      // gate buffer stride (full 16-row layers)
#define GS8 9      // gate buffer stride (8-row L3 passes)

// ---- workspace float offsets (weights in [c][k] concat layout) ----
#define L1W   0
#define L1B   18432
#define L2W   18624
#define L2B   92352
#define L3W   92736
#define L3B   258624
#define L4W   259200
#define L4B   277632
#define F1AW  277824
#define F1AB  278208
#define F1BW  278256
#define F1BB  280560
#define F2AW  280608
#define F2AB  301344
#define F2BW  301488
#define F2BB  315312
#define F3AW  315408
#define F3AB  324624
#define F3BW  324720
#define F3BB  329328
// total 329376 floats = 1.32 MB

// ---- pool float offsets ----
#define P_SAT  0     // sa input, 8x18 = 144
#define P_F1H  144   // f1 hidden, 48x18 = 864 (ends 1008)
#define P_GB   0     // L1/L2/L3 gate buffers (up to 6528)
#define P_F2H  0     // 144x18 = 2592
#define P_O4T  2592  // 96x18 = 1728 (ends 4320)
#define P_F3H  4320  // 96x18 = 1728 (ends 6048)
#define P_OUT5 0     // 48x18 = 864
#define P_L4G  864   // 192x17 = 3264 (ends 4128)
#define POOLSZ 6528

__device__ __forceinline__ float sigf(float x) { return 1.0f / (1.0f + __expf(-x)); }

// ---------------------------------------------------------------------------
// Prep kernels: weights to [c][k] (ih|hh concat for LSTM, zero-padded K for FF)
// ---------------------------------------------------------------------------
__global__ void prep_lstm(const float* __restrict__ wih, const float* __restrict__ whh,
                          const float* __restrict__ bih, const float* __restrict__ bhh,
                          float* __restrict__ W, float* __restrict__ bias,
                          int Din, int H) {
    int K = Din + H;
    int N = 4 * H;
    int total = N * K;
    for (int idx = blockIdx.x * blockDim.x + threadIdx.x; idx < total + N;
         idx += gridDim.x * blockDim.x) {
        if (idx < total) {
            int c = idx / K;
            int k = idx - c * K;
            W[idx] = (k < Din) ? wih[c * Din + k] : whh[c * H + (k - Din)];
        } else {
            int c = idx - total;
            bias[c] = bih[c] + bhh[c];
        }
    }
}

__global__ void prep_ff(const float* __restrict__ w, const float* __restrict__ b,
                        float* __restrict__ W, float* __restrict__ bias,
                        int K, int Kpad, int N) {
    int total = N * Kpad;
    for (int idx = blockIdx.x * blockDim.x + threadIdx.x; idx < total + N;
         idx += gridDim.x * blockDim.x) {
        if (idx < total) {
            int c = idx / Kpad;
            int k = idx - c * Kpad;
            W[idx] = (k < K) ? w[c * K + k] : 0.0f;
        } else {
            int c = idx - total;
            bias[c] = b[c];
        }
    }
}

// ---------------------------------------------------------------------------
// Column matmul: TC columns per thread, ROWS rows. Weight rows streamed from
// global (float4); x^T from LDS (float2 broadcast). Result (+bias, opt relu)
// written to g*[r] (caller bakes column stride into g pointers).
// ---------------------------------------------------------------------------
template <int TC, int ROWS, bool RELU>
__device__ __forceinline__ void mm(
    const float* __restrict__ w0, const float* __restrict__ w1,
    const float* __restrict__ w2,
    float b0, float b1, float b2,
    const float* __restrict__ x0, int K0,
    const float* __restrict__ x1, int K1,
    const float* __restrict__ x2, int K2,
    int rbase,
    float* __restrict__ g0, float* __restrict__ g1, float* __restrict__ g2) {
    float a0[ROWS], a1[ROWS], a2[ROWS];
#pragma unroll
    for (int r = 0; r < ROWS; ++r) { a0[r] = 0.f; a1[r] = 0.f; a2[r] = 0.f; }
    int ko = 0;
#pragma unroll
    for (int s = 0; s < 3; ++s) {
        const float* xb = (s == 0) ? x0 : (s == 1) ? x1 : x2;
        int K = (s == 0) ? K0 : (s == 1) ? K1 : K2;
        if (K > 0) {
            const float* xp = xb + rbase;
#pragma unroll 2
            for (int k = 0; k < K; k += 4) {
                float4 wv0 = *(const float4*)(w0 + ko + k);
                float4 wv1 = (TC > 1) ? *(const float4*)(w1 + ko + k) : wv0;
                float4 wv2 = (TC > 2) ? *(const float4*)(w2 + ko + k) : wv0;
                const float* f0 = (const float*)&wv0;
                const float* f1p = (const float*)&wv1;
                const float* f2p = (const float*)&wv2;
#pragma unroll
                for (int q = 0; q < 4; ++q) {
                    const float* xq = xp + (k + q) * XS;
#pragma unroll
                    for (int rr = 0; rr < ROWS; rr += 2) {
                        float2 xv = *(const float2*)(xq + rr);
                        a0[rr]     = fmaf(xv.x, f0[q], a0[rr]);
                        a0[rr + 1] = fmaf(xv.y, f0[q], a0[rr + 1]);
                        if (TC > 1) {
                            a1[rr]     = fmaf(xv.x, f1p[q], a1[rr]);
                            a1[rr + 1] = fmaf(xv.y, f1p[q], a1[rr + 1]);
                        }
                        if (TC > 2) {
                            a2[rr]     = fmaf(xv.x, f2p[q], a2[rr]);
                            a2[rr + 1] = fmaf(xv.y, f2p[q], a2[rr + 1]);
                        }
                    }
                }
            }
            ko += K;
        }
    }
#pragma unroll
    for (int r = 0; r < ROWS; ++r) {
        float v0 = a0[r] + b0;
        if (RELU) v0 = fmaxf(v0, 0.f);
        g0[r] = v0;
        if (TC > 1) {
            float v1 = a1[r] + b1;
            if (RELU) v1 = fmaxf(v1, 0.f);
            g1[r] = v1;
        }
        if (TC > 2) {
            float v2 = a2[r] + b2;
            if (RELU) v2 = fmaxf(v2, 0.f);
            g2[r] = v2;
        }
    }
}

// ---------------------------------------------------------------------------
// LSTM epilogue: combine i/f/g/o from gate buffer; c-state in regs (fixed
// idx = tid + n*256 ownership); write h into x^T slot.
// ---------------------------------------------------------------------------
template <int H, int R, int NCS>
__device__ __forceinline__ void lstm_epi(const float* __restrict__ gb, int gs,
                                         float* __restrict__ hT, int hrbase,
                                         float (&cs)[NCS], int tid) {
    const int E = H * R;
#pragma unroll
    for (int n = 0; n < NCS; ++n) {
        int idx = tid + n * NT;
        if (idx < E) {
            int r = idx & (R - 1);
            int j = idx / R;
            float gi = gb[j * gs + r];
            float gf = gb[(j + H) * gs + r];
            float gg = gb[(j + 2 * H) * gs + r];
            float go = gb[(j + 3 * H) * gs + r];
            float c2 = sigf(gf) * cs[n] + sigf(gi) * tanhf(gg);
            cs[n] = c2;
            hT[j * XS + hrbase + r] = sigf(go) * tanhf(c2);
        }
    }
}

template <int H, int R, int NCS>
__device__ __forceinline__ void c_init(const float* __restrict__ c0, int r0,
                                       int rbase, float (&cs)[NCS], int tid) {
    const int E = H * R;
#pragma unroll
    for (int n = 0; n < NCS; ++n) {
        int idx = tid + n * NT;
        if (idx < E) {
            int r = idx & (R - 1);
            int j = idx / R;
            cs[n] = c0[(size_t)(r0 + rbase + r) * H + j];
        }
    }
}

// ---------------------------------------------------------------------------
__global__ __launch_bounds__(256, 1) void model_kernel(
    const float* __restrict__ tactiles, const float* __restrict__ actions,
    const float* __restrict__ context, const float* __restrict__ ws,
    const float* __restrict__ h01, const float* __restrict__ c01,
    const float* __restrict__ h02, const float* __restrict__ c02,
    const float* __restrict__ h03, const float* __restrict__ c03,
    const float* __restrict__ h04, const float* __restrict__ c04,
    float* __restrict__ out) {
    __shared__ __align__(16) float tacT[48 * XS];
    __shared__ __align__(16) float ctxT[48 * XS];
    __shared__ __align__(16) float h1T[48 * XS];
    __shared__ __align__(16) float h2T[96 * XS];
    __shared__ __align__(16) float h3T[144 * XS];
    __shared__ __align__(16) float h4T[48 * XS];
    __shared__ __align__(16) float saoT[48 * XS];
    __shared__ __align__(16) float pool[POOLSZ];

    const int tid = threadIdx.x;
    const int r0 = blockIdx.x * MROWS;

    // ---- init h states into x^T slots ----
    for (int i = tid; i < 48 * 16; i += NT) {
        int r = i & 15, j = i >> 4;
        h1T[j * XS + r] = h01[(size_t)(r0 + r) * 48 + j];
        h4T[j * XS + r] = h04[(size_t)(r0 + r) * 48 + j];
    }
    for (int i = tid; i < 96 * 16; i += NT) {
        int r = i & 15, j = i >> 4;
        h2T[j * XS + r] = h02[(size_t)(r0 + r) * 96 + j];
    }
    for (int i = tid; i < 144 * 16; i += NT) {
        int r = i & 15, j = i >> 4;
        h3T[j * XS + r] = h03[(size_t)(r0 + r) * 144 + j];
    }

    // ---- c states in registers ----
    float cs1[3], cs2[6], cs3a[5], cs3b[5], cs4[3];
    c_init<48, 16, 3>(c01, r0, 0, cs1, tid);
    c_init<96, 16, 6>(c02, r0, 0, cs2, tid);
    c_init<144, 8, 5>(c03, r0, 0, cs3a, tid);
    c_init<144, 8, 5>(c03, r0, 8, cs3b, tid);
    c_init<48, 16, 3>(c04, r0, 0, cs4, tid);

    // ---- hoist biases into regs (constant across t) ----
    float bL1  = (tid < 192) ? ws[L1B + tid] : 0.f;
    float bL2a = ws[L2B + tid];
    float bL2b = (tid < 128) ? ws[L2B + tid + 256] : 0.f;
    float bL3a = ws[L3B + tid];
    float bL3b = ws[L3B + tid + 256];
    float bL3c = (tid < 64) ? ws[L3B + tid + 512] : 0.f;
    float bL4  = (tid < 192) ? ws[L4B + tid] : 0.f;
    float bF1a = (tid < 48) ? ws[F1AB + tid] : 0.f;
    float bF1b = (tid < 48) ? ws[F1BB + tid] : 0.f;
    float bF2a = (tid < 144) ? ws[F2AB + tid] : 0.f;
    float bF2b = (tid < 192) ? ws[F2BB + (tid % 96)] : 0.f;
    float bF3a = (tid < 192) ? ws[F3AB + (tid % 96)] : 0.f;
    float bF3b = (tid < 192) ? ws[F3BB + (tid % 48)] : 0.f;

    const int wvid = tid >> 6;
    __syncthreads();

    for (int t = 0; t < TSTEPS; ++t) {
        // ---- stage: tactile (t<6), context, sa ----
        if (t < 6) {
            const float* src = tactiles + (size_t)t * BATCH * 48 + (size_t)r0 * 48;
            for (int i = tid; i < 192; i += NT) {
                int r = i / 12, k4 = (i % 12) * 4;
                float4 v = *(const float4*)(src + r * 48 + k4);
                tacT[(k4 + 0) * XS + r] = v.x;
                tacT[(k4 + 1) * XS + r] = v.y;
                tacT[(k4 + 2) * XS + r] = v.z;
                tacT[(k4 + 3) * XS + r] = v.w;
            }
        }
        {
            const float* src = context + (size_t)t * BATCH * 48 + (size_t)r0 * 48;
            for (int i = tid; i < 192; i += NT) {
                int r = i / 12, k4 = (i % 12) * 4;
                float4 v = *(const float4*)(src + r * 48 + k4);
                ctxT[(k4 + 0) * XS + r] = v.x;
                ctxT[(k4 + 1) * XS + r] = v.y;
                ctxT[(k4 + 2) * XS + r] = v.z;
                ctxT[(k4 + 3) * XS + r] = v.w;
            }
        }
        if (tid < 128) {  // sa = [state=actions[0] | actions[t]] rows 0..5, pad 6..7
            int r = tid & 15, k = tid >> 4;
            float v = 0.f;
            if (k < 3) v = actions[(size_t)(r0 + r) * 3 + k];
            else if (k < 6) v = actions[(size_t)t * BATCH * 3 + (size_t)(r0 + r) * 3 + (k - 3)];
            pool[P_SAT + k * XS + r] = v;
        }
        __syncthreads();

        // ---- f1a: 6(pad8) -> 48, relu ----
        if (tid < 48)
            mm<1, 16, true>(ws + F1AW + tid * 8, ws, ws, bF1a, 0.f, 0.f,
                            pool + P_SAT, 8, nullptr, 0, nullptr, 0, 0,
                            pool + P_F1H + tid * XS, nullptr, nullptr);
        __syncthreads();
        // ---- f1b: 48 -> 48, relu -> saoT ----
        if (tid < 48)
            mm<1, 16, true>(ws + F1BW + tid * 48, ws, ws, bF1b, 0.f, 0.f,
                            pool + P_F1H, 48, nullptr, 0, nullptr, 0, 0,
                            saoT + tid * XS, nullptr, nullptr);
        __syncthreads();

        // ---- L1: x=[x1|h1] ----
        {
            const float* x1 = (t < 6) ? tacT : h4T;
            if (tid < 192)
                mm<1, 16, false>(ws + L1W + tid * 96, ws, ws, bL1, 0.f, 0.f,
                                 x1, 48, h1T, 48, nullptr, 0, 0,
                                 pool + P_GB + tid * GS, nullptr, nullptr);
        }
        __syncthreads();
        lstm_epi<48, 16, 3>(pool + P_GB, GS, h1T, 0, cs1, tid);
        __syncthreads();

        // ---- L2: x=[ctx|h1|h2] ----
        if (wvid < 2)
            mm<2, 16, false>(ws + L2W + (size_t)tid * 192, ws + L2W + (size_t)(tid + 256) * 192,
                             ws, bL2a, bL2b, 0.f,
                             ctxT, 48, h1T, 48, h2T, 96, 0,
                             pool + P_GB + tid * GS, pool + P_GB + (tid + 256) * GS, nullptr);
        else
            mm<1, 16, false>(ws + L2W + (size_t)tid * 192, ws, ws, bL2a, 0.f, 0.f,
                             ctxT, 48, h1T, 48, h2T, 96, 0,
                             pool + P_GB + tid * GS, nullptr, nullptr);
        __syncthreads();
        lstm_epi<96, 16, 6>(pool + P_GB, GS, h2T, 0, cs2, tid);
        __syncthreads();

        // ---- L3: x=[sa_out|h2|h3], two 8-row passes ----
        if (wvid == 0)
            mm<3, 8, false>(ws + L3W + (size_t)tid * 288, ws + L3W + (size_t)(tid + 256) * 288,
                            ws + L3W + (size_t)(tid + 512) * 288, bL3a, bL3b, bL3c,
                            saoT, 48, h2T, 96, h3T, 144, 0,
                            pool + P_GB + tid * GS8, pool + P_GB + (tid + 256) * GS8,
                            pool + P_GB + (tid + 512) * GS8);
        else
            mm<2, 8, false>(ws + L3W + (size_t)tid * 288, ws + L3W + (size_t)(tid + 256) * 288,
                            ws, bL3a, bL3b, 0.f,
                            saoT, 48, h2T, 96, h3T, 144, 0,
                            pool + P_GB + tid * GS8, pool + P_GB + (tid + 256) * GS8, nullptr);
        __syncthreads();
        lstm_epi<144, 8, 5>(pool + P_GB, GS8, h3T, 0, cs3a, tid);
        __syncthreads();
        if (wvid == 0)
            mm<3, 8, false>(ws + L3W + (size_t)tid * 288, ws + L3W + (size_t)(tid + 256) * 288,
                            ws + L3W + (size_t)(tid + 512) * 288, bL3a, bL3b, bL3c,
                            saoT, 48, h2T, 96, h3T, 144, 8,
                            pool + P_GB + tid * GS8, pool + P_GB + (tid + 256) * GS8,
                            pool + P_GB + (tid + 512) * GS8);
        else
            mm<2, 8, false>(ws + L3W + (size_t)tid * 288, ws + L3W + (size_t)(tid + 256) * 288,
                            ws, bL3a, bL3b, 0.f,
                            saoT, 48, h2T, 96, h3T, 144, 8,
                            pool + P_GB + tid * GS8, pool + P_GB + (tid + 256) * GS8, nullptr);
        __syncthreads();
        lstm_epi<144, 8, 5>(pool + P_GB, GS8, h3T, 8, cs3b, tid);
        __syncthreads();

        // ---- f2a: 144 -> 144, relu ----
        if (tid < 144)
            mm<1, 16, true>(ws + F2AW + tid * 144, ws, ws, bF2a, 0.f, 0.f,
                            h3T, 144, nullptr, 0, nullptr, 0, 0,
                            pool + P_F2H + tid * XS, nullptr, nullptr);
        __syncthreads();
        // ---- f2b: 144 -> 96, relu (8-row halves) ----
        if (tid < 192) {
            int c = tid % 96, rb = (tid / 96) * 8;
            mm<1, 8, true>(ws + F2BW + c * 144, ws, ws, bF2b, 0.f, 0.f,
                           pool + P_F2H, 144, nullptr, 0, nullptr, 0, rb,
                           pool + P_O4T + c * XS + rb, nullptr, nullptr);
        }
        __syncthreads();
        // ---- f3a: 96 -> 96, relu ----
        if (tid < 192) {
            int c = tid % 96, rb = (tid / 96) * 8;
            mm<1, 8, true>(ws + F3AW + c * 96, ws, ws, bF3a, 0.f, 0.f,
                           pool + P_O4T, 96, nullptr, 0, nullptr, 0, rb,
                           pool + P_F3H + c * XS + rb, nullptr, nullptr);
        }
        __syncthreads();
        // ---- f3b: 96 -> 48, relu (4-row quarters) -> out5 ----
        if (tid < 192) {
            int c = tid % 48, rb = (tid / 48) * 4;
            mm<1, 4, true>(ws + F3BW + c * 96, ws, ws, bF3b, 0.f, 0.f,
                           pool + P_F3H, 96, nullptr, 0, nullptr, 0, rb,
                           pool + P_OUT5 + c * XS + rb, nullptr, nullptr);
        }
        __syncthreads();

        // ---- L4: x=[out5|h4] ----
        if (tid < 192)
            mm<1, 16, false>(ws + L4W + tid * 96, ws, ws, bL4, 0.f, 0.f,
                             pool + P_OUT5, 48, h4T, 48, nullptr, 0, 0,
                             pool + P_L4G + tid * GS, nullptr, nullptr);
        __syncthreads();
        lstm_epi<48, 16, 3>(pool + P_L4G, GS, h4T, 0, cs4, tid);
        __syncthreads();

        // ---- emit h4 ----
        {
            float* dst = out + (size_t)t * BATCH * 48 + (size_t)r0 * 48;
            for (int i = tid; i < 192; i += NT) {
                int r = i / 12, j4 = (i % 12) * 4;
                float4 v;
                v.x = h4T[(j4 + 0) * XS + r];
                v.y = h4T[(j4 + 1) * XS + r];
                v.z = h4T[(j4 + 2) * XS + r];
                v.w = h4T[(j4 + 3) * XS + r];
                *(float4*)(dst + r * 48 + j4) = v;
            }
        }
        __syncthreads();
    }
}

// ---------------------------------------------------------------------------
extern "C" void kernel_launch(void* const* d_in, const int* in_sizes, int n_in,
                              void* d_out, int out_size, void* d_ws, size_t ws_size,
                              hipStream_t stream) {
    const float* tac = (const float*)d_in[0];
    const float* act = (const float*)d_in[1];
    const float* ctx = (const float*)d_in[2];

    const float* l1_wih = (const float*)d_in[3];
    const float* l1_whh = (const float*)d_in[4];
    const float* l1_bih = (const float*)d_in[5];
    const float* l1_bhh = (const float*)d_in[6];
    const float* l2_wih = (const float*)d_in[7];
    const float* l2_whh = (const float*)d_in[8];
    const float* l2_bih = (const float*)d_in[9];
    const float* l2_bhh = (const float*)d_in[10];
    const float* l3_wih = (const float*)d_in[11];
    const float* l3_whh = (const float*)d_in[12];
    const float* l3_bih = (const float*)d_in[13];
    const float* l3_bhh = (const float*)d_in[14];
    const float* l4_wih = (const float*)d_in[15];
    const float* l4_whh = (const float*)d_in[16];
    const float* l4_bih = (const float*)d_in[17];
    const float* l4_bhh = (const float*)d_in[18];

    const float* f1_w1 = (const float*)d_in[19];
    const float* f1_b1 = (const float*)d_in[20];
    const float* f1_w2 = (const float*)d_in[21];
    const float* f1_b2 = (const float*)d_in[22];
    const float* f2_w1 = (const float*)d_in[23];
    const float* f2_b1 = (const float*)d_in[24];
    const float* f2_w2 = (const float*)d_in[25];
    const float* f2_b2 = (const float*)d_in[26];
    const float* f3_w1 = (const float*)d_in[27];
    const float* f3_b1 = (const float*)d_in[28];
    const float* f3_w2 = (const float*)d_in[29];
    const float* f3_b2 = (const float*)d_in[30];

    const float* h01 = (const float*)d_in[31];
    const float* c01 = (const float*)d_in[32];
    const float* h02 = (const float*)d_in[33];
    const float* c02 = (const float*)d_in[34];
    const float* h03 = (const float*)d_in[35];
    const float* c03 = (const float*)d_in[36];
    const float* h04 = (const float*)d_in[37];
    const float* c04 = (const float*)d_in[38];

    float* ws = (float*)d_ws;
    float* out = (float*)d_out;

    dim3 blk(NT);
    hipLaunchKernelGGL(prep_lstm, dim3(96), blk, 0, stream,
                       l1_wih, l1_whh, l1_bih, l1_bhh, ws + L1W, ws + L1B, 48, 48);
    hipLaunchKernelGGL(prep_lstm, dim3(256), blk, 0, stream,
                       l2_wih, l2_whh, l2_bih, l2_bhh, ws + L2W, ws + L2B, 96, 96);
    hipLaunchKernelGGL(prep_lstm, dim3(256), blk, 0, stream,
                       l3_wih, l3_whh, l3_bih, l3_bhh, ws + L3W, ws + L3B, 144, 144);
    hipLaunchKernelGGL(prep_lstm, dim3(96), blk, 0, stream,
                       l4_wih, l4_whh, l4_bih, l4_bhh, ws + L4W, ws + L4B, 48, 48);

    hipLaunchKernelGGL(prep_ff, dim3(4), blk, 0, stream,
                       f1_w1, f1_b1, ws + F1AW, ws + F1AB, 6, 8, 48);
    hipLaunchKernelGGL(prep_ff, dim3(16), blk, 0, stream,
                       f1_w2, f1_b2, ws + F1BW, ws + F1BB, 48, 48, 48);
    hipLaunchKernelGGL(prep_ff, dim3(96), blk, 0, stream,
                       f2_w1, f2_b1, ws + F2AW, ws + F2AB, 144, 144, 144);
    hipLaunchKernelGGL(prep_ff, dim3(64), blk, 0, stream,
                       f2_w2, f2_b2, ws + F2BW, ws + F2BB, 144, 144, 96);
    hipLaunchKernelGGL(prep_ff, dim3(48), blk, 0, stream,
                       f3_w1, f3_b1, ws + F3AW, ws + F3AB, 96, 96, 96);
    hipLaunchKernelGGL(prep_ff, dim3(24), blk, 0, stream,
                       f3_w2, f3_b2, ws + F3BW, ws + F3BB, 96, 96, 48);

    hipLaunchKernelGGL(model_kernel, dim3(BATCH / MROWS), blk, 0, stream,
                       tac, act, ctx, ws,
                       h01, c01, h02, c02, h03, c03, h04, c04, out);
}